// Round 1
// baseline (216.474 us; speedup 1.0000x reference)
//
#include <hip/hip_runtime.h>
#include <stdint.h>

#define NB 8
#define NN 2048
#define FF 128
#define ALPHA 0.2f

typedef unsigned short u16;
typedef __attribute__((ext_vector_type(8))) short bf16x8;  // 8 bf16, 4 VGPRs
typedef __attribute__((ext_vector_type(4))) float f32x4;

__device__ __forceinline__ float bf2f(u16 h) {
    union { uint32_t u; float f; } v; v.u = ((uint32_t)h) << 16; return v.f;
}
__device__ __forceinline__ u16 f2bf(float x) {
    union { float f; uint32_t u; } v; v.f = x;
    uint32_t r = v.u + 0x7fffu + ((v.u >> 16) & 1u);  // RNE
    return (u16)(r >> 16);
}
__device__ __forceinline__ uint4 pack8(const float o[8]) {
    uint4 r;
    r.x = (uint32_t)f2bf(o[0]) | ((uint32_t)f2bf(o[1]) << 16);
    r.y = (uint32_t)f2bf(o[2]) | ((uint32_t)f2bf(o[3]) << 16);
    r.z = (uint32_t)f2bf(o[4]) | ((uint32_t)f2bf(o[5]) << 16);
    r.w = (uint32_t)f2bf(o[6]) | ((uint32_t)f2bf(o[7]) << 16);
    return r;
}
__device__ __forceinline__ void load8f(const float* p, size_t i, float o[8]) {
    float4 a = *(const float4*)(p + i);
    float4 b = *(const float4*)(p + i + 4);
    o[0]=a.x; o[1]=a.y; o[2]=a.z; o[3]=a.w;
    o[4]=b.x; o[5]=b.y; o[6]=b.z; o[7]=b.w;
}

// async global->LDS, 16 B per lane, dest = wave-uniform base + lane*16
__device__ __forceinline__ void gload_lds16(const void* g, void* l) {
    __builtin_amdgcn_global_load_lds(
        (const __attribute__((address_space(1))) void*)g,
        (__attribute__((address_space(3))) void*)l,
        16, 0, 0);
}

// ---------------------------------------------------------------------------
// Kernel 1: prep. h = x·W^T via MFMA (bf16 in, fp32 acc) -> hT[b][o][n] bf16
// (coalesced via LDS bounce); src/dst = x·(W^T a) accumulated in fp32 during
// x staging (fp32-exact scores — R6-validated numerics).
// 256 blocks = 8 b x 32 n-tiles(64), b = bid&7 so each XCD owns one batch.
// ---------------------------------------------------------------------------
__global__ __launch_bounds__(256) void k_prep(
    const float* __restrict__ x,    // [B][N][F]
    const float* __restrict__ w,    // [F][F] o-major
    const float* __restrict__ as_,  // [F]
    const float* __restrict__ ad_,  // [F]
    u16* __restrict__ hT,           // [B][F][N] bf16
    float* __restrict__ srcp, float* __restrict__ dstp)
{
    __shared__ __attribute__((aligned(16))) u16 Ws[128][136];   // also bounce buf
    __shared__ __attribute__((aligned(16))) u16 Xs[64][136];
    __shared__ float waS[128], waD[128];
    __shared__ float lredS[64][4], lredD[64][4];

    const int b  = blockIdx.x & 7;            // XCD-grouped
    const int n0 = (blockIdx.x >> 3) * 64;
    const int t  = threadIdx.x;
    const int wv = t >> 6, lane = t & 63, quad = lane >> 4, lr = lane & 15;

    // stage W (bf16)
    {
        const int o = t >> 1, fb = (t & 1) * 64;
        #pragma unroll
        for (int k = 0; k < 8; ++k) {
            float v8[8];
            load8f(w, (size_t)o * FF + fb + k * 8, v8);
            *(uint4*)&Ws[o][fb + k * 8] = pack8(v8);
        }
    }
    // waS/waD = W^T a (fp32, from global)
    if (t < 128) {
        float s = 0.f;
        for (int o = 0; o < FF; ++o) s += w[(size_t)o * FF + t] * as_[o];
        waS[t] = s;
    } else {
        const int f = t - 128;
        float s = 0.f;
        for (int o = 0; o < FF; ++o) s += w[(size_t)o * FF + f] * ad_[o];
        waD[f] = s;
    }
    __syncthreads();

    // stage x tile (bf16) + fp32 src/dst partials
    {
        const int r = t >> 2, q = t & 3;
        float sp = 0.f, dp = 0.f;
        #pragma unroll
        for (int k = 0; k < 4; ++k) {
            float v8[8];
            load8f(x, (size_t)(b * NN + n0 + r) * FF + q * 32 + k * 8, v8);
            *(uint4*)&Xs[r][q * 32 + k * 8] = pack8(v8);
            #pragma unroll
            for (int u = 0; u < 8; ++u) {
                sp += v8[u] * waS[q * 32 + k * 8 + u];
                dp += v8[u] * waD[q * 32 + k * 8 + u];
            }
        }
        lredS[r][q] = sp; lredD[r][q] = dp;
    }
    __syncthreads();
    if (t < 64) {
        srcp[b * NN + n0 + t] = lredS[t][0] + lredS[t][1] + lredS[t][2] + lredS[t][3];
        dstp[b * NN + n0 + t] = lredD[t][0] + lredD[t][1] + lredD[t][2] + lredD[t][3];
    }

    // h MFMA: wave wv owns n-rows wv*16..+15
    f32x4 hacc[8] = {};
    #pragma unroll
    for (int kc = 0; kc < 4; ++kc) {
        const int ko = kc * 32 + quad * 8;
        bf16x8 a = *(const bf16x8*)&Xs[wv * 16 + lr][ko];
        #pragma unroll
        for (int t8 = 0; t8 < 8; ++t8) {
            bf16x8 bb = *(const bf16x8*)&Ws[t8 * 16 + lr][ko];
            hacc[t8] = __builtin_amdgcn_mfma_f32_16x16x32_bf16(a, bb, hacc[t8], 0, 0, 0);
        }
    }
    __syncthreads();   // all MFMA LDS reads done; Ws reusable as bounce buffer

    // bounce acc -> HsB[o][nl] (stride 68), then coalesced copy to hT
    u16* HsB = &Ws[0][0];
    #pragma unroll
    for (int t8 = 0; t8 < 8; ++t8) {
        #pragma unroll
        for (int reg = 0; reg < 4; ++reg)
            HsB[(t8 * 16 + lr) * 68 + wv * 16 + quad * 4 + reg] = f2bf(hacc[t8][reg]);
    }
    __syncthreads();
    {
        const int r16 = t >> 4, ng = t & 15;
        #pragma unroll
        for (int s = 0; s < 8; ++s) {
            const int o = s * 16 + r16;
            uint2 v = *(const uint2*)&HsB[o * 68 + ng * 4];
            *(uint2*)&hT[(size_t)(b * FF + o) * NN + n0 + ng * 4] = v;
        }
    }
}

// ---------------------------------------------------------------------------
// Kernel 2: attention. 512 blocks = 8 b x 64 i-tiles(32), b = bid&7 so each
// XCD owns one batch (hT[b] slice = 512 KB -> L2-resident per XCD).
// 256 threads = 4 waves; ~43 KB LDS -> 3 blocks/CU.
// j-loop of 128 with 2 barriers/iter:
//   - Hs staged via global_load_lds (fire-and-forget, issued BEFORE P-gen so
//     the exp/pack VALU hides staging latency). LDS image is XOR-swizzled
//     (slot ^ (row&7)) via pre-swizzled per-lane GLOBAL source (rule 21);
//     reads apply the same involution -> bank-uniform ds_read_b128.
//   - P = adj ? exp(lrelu(src_i+dst_j)) : 0 -> Ps bf16 (denominator sums the
//     same bf16-rounded p); PV: 16 MFMA/wave under setprio(1).
// Epilogue: ELU(acc/l) -> fp32 out.
// ---------------------------------------------------------------------------
__global__ __launch_bounds__(256) void k_attn(
    const int*   __restrict__ adj,   // [B][N][N]
    const u16*   __restrict__ hT,    // [B][F][N] bf16
    const float* __restrict__ srcp,
    const float* __restrict__ dstp,
    float* __restrict__ out)         // [B][N][F] fp32
{
    __shared__ __attribute__((aligned(16))) u16 Hs[128][128];  // linear rows, swizzled content
    __shared__ __attribute__((aligned(16))) u16 Ps[32][136];
    __shared__ float lred[32][8];
    __shared__ float lrowS[32];

    const int b  = blockIdx.x & 7;            // XCD-grouped
    const int i0 = (blockIdx.x >> 3) * 32;
    const int t  = threadIdx.x;
    const int wv = t >> 6, lane = t & 63, quad = lane >> 4, lr = lane & 15;
    const int rowt = (wv & 1) * 16, colt = (wv >> 1) * 64;

    const int il = t >> 3, q = t & 7;            // P-gen: row il, 16 j's at q*16
    const float src_i  = srcp[b * NN + i0 + il];
    const int*   adjrow = adj + (size_t)(b * NN + i0 + il) * NN;
    const float* dstb   = dstp + b * NN;

    // staging decode: one global_load_lds writes 4 rows x 16 slots (1024 B)
    const int lrow4 = lane >> 4, sl = lane & 15;
    const u16* hTb = hT + (size_t)(b * FF) * NN;
    const int sw = lr & 7;                        // read-side swizzle (row & 7)

    f32x4 acc[4] = {};
    float lacc = 0.f;

    for (int j0 = 0; j0 < NN; j0 += 128) {
        // stage Hs: wave wv owns rows [wv*32, wv*32+32). LDS dest linear
        // (HW: base + lane*16); global source column pre-swizzled so that
        // LDS[row][s] holds logical slot s ^ (row&7).
        #pragma unroll
        for (int i = 0; i < 8; ++i) {
            const int o  = wv * 32 + i * 4 + lrow4;
            const int sg = sl ^ (o & 7);
            gload_lds16(hTb + (size_t)o * NN + j0 + sg * 8, &Hs[wv * 32 + i * 4][0]);
        }
        // P-gen (overlaps in-flight staging): thread (il, q) covers 16 j's
        {
            int4   a4[4]; float4 d4[4];
            #pragma unroll
            for (int it = 0; it < 4; ++it) {
                a4[it] = *(const int4*)(adjrow + j0 + q * 16 + it * 4);
                d4[it] = *(const float4*)(dstb + j0 + q * 16 + it * 4);
            }
            u16 pb[16];
            #pragma unroll
            for (int it = 0; it < 4; ++it) {
                const int*   ai = (const int*)&a4[it];
                const float* dv = (const float*)&d4[it];
                #pragma unroll
                for (int u = 0; u < 4; ++u) {
                    float e = src_i + dv[u];
                    e = e > 0.f ? e : ALPHA * e;
                    float p = __expf(e);
                    p = (ai[u] > 0) ? p : 0.f;
                    const u16 pv = f2bf(p);
                    pb[it * 4 + u] = pv;
                    lacc += bf2f(pv);           // denom == numerator's P exactly
                }
            }
            uint4 w0, w1;
            w0.x = (uint32_t)pb[0]  | ((uint32_t)pb[1]  << 16);
            w0.y = (uint32_t)pb[2]  | ((uint32_t)pb[3]  << 16);
            w0.z = (uint32_t)pb[4]  | ((uint32_t)pb[5]  << 16);
            w0.w = (uint32_t)pb[6]  | ((uint32_t)pb[7]  << 16);
            w1.x = (uint32_t)pb[8]  | ((uint32_t)pb[9]  << 16);
            w1.y = (uint32_t)pb[10] | ((uint32_t)pb[11] << 16);
            w1.z = (uint32_t)pb[12] | ((uint32_t)pb[13] << 16);
            w1.w = (uint32_t)pb[14] | ((uint32_t)pb[15] << 16);
            *(uint4*)&Ps[il][q * 16]     = w0;
            *(uint4*)&Ps[il][q * 16 + 8] = w1;
        }
        __syncthreads();   // drains vmcnt(0): Hs (async) + Ps visible

        // PV: wave (rowt, colt): acc += P[rowt..+16] · h[colt..+64]
        __builtin_amdgcn_s_setprio(1);
        #pragma unroll
        for (int kc = 0; kc < 4; ++kc) {
            const int ko = kc * 32 + quad * 8;
            bf16x8 a = *(const bf16x8*)&Ps[rowt + lr][ko];
            #pragma unroll
            for (int t8 = 0; t8 < 4; ++t8) {
                // row = colt + t8*16 + lr; (row & 7) == (lr & 7) == sw
                bf16x8 bb = *(const bf16x8*)&Hs[colt + t8 * 16 + lr][((kc * 4 + quad) ^ sw) * 8];
                acc[t8] = __builtin_amdgcn_mfma_f32_16x16x32_bf16(a, bb, acc[t8], 0, 0, 0);
            }
        }
        __builtin_amdgcn_s_setprio(0);
        __syncthreads();   // PV reads done before next overwrite
    }

    lred[il][q] = lacc;
    __syncthreads();
    if (t < 32) {
        float s = 0.f;
        #pragma unroll
        for (int k = 0; k < 8; ++k) s += lred[t][k];
        lrowS[t] = s;
    }
    __syncthreads();

    // epilogue: normalize, ELU, fp32 store
    #pragma unroll
    for (int t8 = 0; t8 < 4; ++t8) {
        const int col = colt + t8 * 16 + lr;
        #pragma unroll
        for (int reg = 0; reg < 4; ++reg) {
            const int row = rowt + quad * 4 + reg;
            const float l = fmaxf(lrowS[row], 1e-30f);
            float v = acc[t8][reg] / l;
            v = v > 0.f ? v : __expf(v) - 1.f;
            out[(size_t)(b * NN + i0 + row) * FF + col] = v;
        }
    }
}

// ---------------------------------------------------------------------------
extern "C" void kernel_launch(void* const* d_in, const int* in_sizes, int n_in,
                              void* d_out, int out_size, void* d_ws, size_t ws_size,
                              hipStream_t stream) {
    const float* x = nullptr; const int* adj = nullptr; const float* w = nullptr;
    const float* as_ = nullptr; const float* ad_ = nullptr;
    for (int i = 0; i < n_in; ++i) {
        const long long s = in_sizes[i];
        if      (s == (long long)NB * NN * FF)  x   = (const float*)d_in[i];
        else if (s == (long long)NB * NN * NN)  adj = (const int*)d_in[i];
        else if (s == FF * FF)                  w   = (const float*)d_in[i];
        else if (s == FF) { if (!as_) as_ = (const float*)d_in[i]; else ad_ = (const float*)d_in[i]; }
    }
    if (!x)   x   = (const float*)d_in[0];
    if (!adj) adj = (const int*)d_in[1];
    if (!w)   w   = (const float*)d_in[2];
    if (!as_) as_ = (const float*)d_in[3];
    if (!ad_) ad_ = (const float*)d_in[4];
    float* out = (float*)d_out;

    u16*   hT   = (u16*)d_ws;                              // 4 MiB
    float* srcp = (float*)((char*)d_ws + (size_t)NB * FF * NN * sizeof(u16));
    float* dstp = srcp + NB * NN;                          // 64 KiB each

    k_prep<<<256, 256, 0, stream>>>(x, w, as_, ad_, hT, srcp, dstp);
    k_attn<<<512, 256, 0, stream>>>(adj, hT, srcp, dstp, out);
}

// Round 2
// 215.062 us; speedup vs baseline: 1.0066x; 1.0066x over previous
//
#include <hip/hip_runtime.h>
#include <stdint.h>

#define NB 8
#define NN 2048
#define FF 128
#define ALPHA 0.2f

typedef unsigned short u16;
typedef __attribute__((ext_vector_type(8))) short bf16x8;  // 8 bf16, 4 VGPRs
typedef __attribute__((ext_vector_type(4))) float f32x4;
typedef __attribute__((ext_vector_type(4))) int   i32x4;

__device__ __forceinline__ float bf2f(u16 h) {
    union { uint32_t u; float f; } v; v.u = ((uint32_t)h) << 16; return v.f;
}
__device__ __forceinline__ u16 f2bf(float x) {
    union { float f; uint32_t u; } v; v.f = x;
    uint32_t r = v.u + 0x7fffu + ((v.u >> 16) & 1u);  // RNE
    return (u16)(r >> 16);
}
__device__ __forceinline__ uint4 pack8(const float o[8]) {
    uint4 r;
    r.x = (uint32_t)f2bf(o[0]) | ((uint32_t)f2bf(o[1]) << 16);
    r.y = (uint32_t)f2bf(o[2]) | ((uint32_t)f2bf(o[3]) << 16);
    r.z = (uint32_t)f2bf(o[4]) | ((uint32_t)f2bf(o[5]) << 16);
    r.w = (uint32_t)f2bf(o[6]) | ((uint32_t)f2bf(o[7]) << 16);
    return r;
}
__device__ __forceinline__ void load8f(const float* p, size_t i, float o[8]) {
    float4 a = *(const float4*)(p + i);
    float4 b = *(const float4*)(p + i + 4);
    o[0]=a.x; o[1]=a.y; o[2]=a.z; o[3]=a.w;
    o[4]=b.x; o[5]=b.y; o[6]=b.z; o[7]=b.w;
}

// async global->LDS, 16 B per lane, dest = wave-uniform base + lane*16
__device__ __forceinline__ void gload_lds16(const void* g, void* l) {
    __builtin_amdgcn_global_load_lds(
        (const __attribute__((address_space(1))) void*)g,
        (__attribute__((address_space(3))) void*)l,
        16, 0, 0);
}

// 4x dwordx4 prefetch loads, pinned program order (volatile asm) so the
// manual vmcnt ledger in k_attn stays valid.
__device__ __forceinline__ void ld4x16_i(const void* p, i32x4& a0, i32x4& a1, i32x4& a2, i32x4& a3) {
    asm volatile(
        "global_load_dwordx4 %0, %4, off\n\t"
        "global_load_dwordx4 %1, %4, off offset:16\n\t"
        "global_load_dwordx4 %2, %4, off offset:32\n\t"
        "global_load_dwordx4 %3, %4, off offset:48"
        : "=&v"(a0), "=&v"(a1), "=&v"(a2), "=&v"(a3)
        : "v"(p));
}
__device__ __forceinline__ void ld4x16_f(const void* p, f32x4& d0, f32x4& d1, f32x4& d2, f32x4& d3) {
    asm volatile(
        "global_load_dwordx4 %0, %4, off\n\t"
        "global_load_dwordx4 %1, %4, off offset:16\n\t"
        "global_load_dwordx4 %2, %4, off offset:32\n\t"
        "global_load_dwordx4 %3, %4, off offset:48"
        : "=&v"(d0), "=&v"(d1), "=&v"(d2), "=&v"(d3)
        : "v"(p));
}

// ---------------------------------------------------------------------------
// Kernel 1: prep. h = x·W^T via MFMA (bf16 in, fp32 acc) -> hT[b][o][n] bf16
// (coalesced via LDS bounce); src/dst = x·(W^T a) accumulated in fp32 during
// x staging (fp32-exact scores — R6-validated numerics).
// 256 blocks = 8 b x 32 n-tiles(64), b = bid&7 so each XCD owns one batch.
// ---------------------------------------------------------------------------
__global__ __launch_bounds__(256) void k_prep(
    const float* __restrict__ x,    // [B][N][F]
    const float* __restrict__ w,    // [F][F] o-major
    const float* __restrict__ as_,  // [F]
    const float* __restrict__ ad_,  // [F]
    u16* __restrict__ hT,           // [B][F][N] bf16
    float* __restrict__ srcp, float* __restrict__ dstp)
{
    __shared__ __attribute__((aligned(16))) u16 Ws[128][136];   // also bounce buf
    __shared__ __attribute__((aligned(16))) u16 Xs[64][136];
    __shared__ float waS[128], waD[128];
    __shared__ float lredS[64][4], lredD[64][4];

    const int b  = blockIdx.x & 7;            // XCD-grouped
    const int n0 = (blockIdx.x >> 3) * 64;
    const int t  = threadIdx.x;
    const int wv = t >> 6, lane = t & 63, quad = lane >> 4, lr = lane & 15;

    // stage W (bf16)
    {
        const int o = t >> 1, fb = (t & 1) * 64;
        #pragma unroll
        for (int k = 0; k < 8; ++k) {
            float v8[8];
            load8f(w, (size_t)o * FF + fb + k * 8, v8);
            *(uint4*)&Ws[o][fb + k * 8] = pack8(v8);
        }
    }
    // waS/waD = W^T a (fp32, from global)
    if (t < 128) {
        float s = 0.f;
        for (int o = 0; o < FF; ++o) s += w[(size_t)o * FF + t] * as_[o];
        waS[t] = s;
    } else {
        const int f = t - 128;
        float s = 0.f;
        for (int o = 0; o < FF; ++o) s += w[(size_t)o * FF + f] * ad_[o];
        waD[f] = s;
    }
    __syncthreads();

    // stage x tile (bf16) + fp32 src/dst partials
    {
        const int r = t >> 2, q = t & 3;
        float sp = 0.f, dp = 0.f;
        #pragma unroll
        for (int k = 0; k < 4; ++k) {
            float v8[8];
            load8f(x, (size_t)(b * NN + n0 + r) * FF + q * 32 + k * 8, v8);
            *(uint4*)&Xs[r][q * 32 + k * 8] = pack8(v8);
            #pragma unroll
            for (int u = 0; u < 8; ++u) {
                sp += v8[u] * waS[q * 32 + k * 8 + u];
                dp += v8[u] * waD[q * 32 + k * 8 + u];
            }
        }
        lredS[r][q] = sp; lredD[r][q] = dp;
    }
    __syncthreads();
    if (t < 64) {
        srcp[b * NN + n0 + t] = lredS[t][0] + lredS[t][1] + lredS[t][2] + lredS[t][3];
        dstp[b * NN + n0 + t] = lredD[t][0] + lredD[t][1] + lredD[t][2] + lredD[t][3];
    }

    // h MFMA: wave wv owns n-rows wv*16..+15
    f32x4 hacc[8] = {};
    #pragma unroll
    for (int kc = 0; kc < 4; ++kc) {
        const int ko = kc * 32 + quad * 8;
        bf16x8 a = *(const bf16x8*)&Xs[wv * 16 + lr][ko];
        #pragma unroll
        for (int t8 = 0; t8 < 8; ++t8) {
            bf16x8 bb = *(const bf16x8*)&Ws[t8 * 16 + lr][ko];
            hacc[t8] = __builtin_amdgcn_mfma_f32_16x16x32_bf16(a, bb, hacc[t8], 0, 0, 0);
        }
    }
    __syncthreads();   // all MFMA LDS reads done; Ws reusable as bounce buffer

    // bounce acc -> HsB[o][nl] (stride 68), then coalesced copy to hT
    u16* HsB = &Ws[0][0];
    #pragma unroll
    for (int t8 = 0; t8 < 8; ++t8) {
        #pragma unroll
        for (int reg = 0; reg < 4; ++reg)
            HsB[(t8 * 16 + lr) * 68 + wv * 16 + quad * 4 + reg] = f2bf(hacc[t8][reg]);
    }
    __syncthreads();
    {
        const int r16 = t >> 4, ng = t & 15;
        #pragma unroll
        for (int s = 0; s < 8; ++s) {
            const int o = s * 16 + r16;
            uint2 v = *(const uint2*)&HsB[o * 68 + ng * 4];
            *(uint2*)&hT[(size_t)(b * FF + o) * NN + n0 + ng * 4] = v;
        }
    }
}

// ---------------------------------------------------------------------------
// Kernel 2: attention. 512 blocks = 8 b x 64 i-tiles(32), b = bid&7 (XCD-
// pinned). 256 threads = 4 waves; ~42.6 KB LDS -> 3 blocks/CU.
//
// Pipelined j-loop (raw barriers + counted vmcnt, T3/T4+T14):
//   per-wave VMEM ledger entering iter t: [adj(t) x8 oldest][glds(t) x8]
//   1. vmcnt(8)            -> adj(t)/dst(t) regs valid
//   2. P-gen(t) from regs; ds_write Ps
//   3. issue adj/dst(t+1)  (stay in flight across both barriers)
//   4. vmcnt(8) lgkmcnt(0) -> glds(t) landed in Hs; Ps visible; s_barrier
//   5. MFMA (setprio 1)
//   6. lgkmcnt(0); s_barrier  -> Hs/Ps free to overwrite
//   7. issue glds(t+1) into Hs
//   last iter: step 4 uses vmcnt(0); steps 3/7 skipped.
// All waits volatile asm + sched_barrier(0) fences (rule 18). Only asm /
// gload_lds VMEM inside the loop -> ledger exact; compiler waits can only
// over-wait. Numerics identical to the 216 us version.
// ---------------------------------------------------------------------------
__global__ __launch_bounds__(256, 3) void k_attn(
    const int*   __restrict__ adj,   // [B][N][N]
    const u16*   __restrict__ hT,    // [B][F][N] bf16
    const float* __restrict__ srcp,
    const float* __restrict__ dstp,
    float* __restrict__ out)         // [B][N][F] fp32
{
    __shared__ __attribute__((aligned(16))) u16 Hs[128][128];  // linear rows, swizzled content
    __shared__ __attribute__((aligned(16))) u16 Ps[32][136];
    __shared__ float lred[32][8];
    __shared__ float lrowS[32];

    const int b  = blockIdx.x & 7;            // XCD-grouped
    const int i0 = (blockIdx.x >> 3) * 32;
    const int t  = threadIdx.x;
    const int wv = t >> 6, lane = t & 63, quad = lane >> 4, lr = lane & 15;
    const int rowt = (wv & 1) * 16, colt = (wv >> 1) * 64;

    const int il = t >> 3, q = t & 7;            // P-gen: row il, 16 j's at q*16
    const float src_i  = srcp[b * NN + i0 + il];
    const int*   adjrow = adj + (size_t)(b * NN + i0 + il) * NN;
    const float* dstb   = dstp + b * NN;

    // staging decode: one global_load_lds writes 4 rows x 16 slots (1024 B)
    const int lrow4 = lane >> 4, sl = lane & 15;
    const u16* hTb = hT + (size_t)(b * FF) * NN;
    const int sw = lr & 7;                        // read-side swizzle (row & 7)

    f32x4 acc[4] = {};
    float lacc = 0.f;

    #define STAGE_HS(J0) { \
        _Pragma("unroll") for (int i_ = 0; i_ < 8; ++i_) { \
            const int o_  = wv * 32 + i_ * 4 + lrow4; \
            const int sg_ = sl ^ (o_ & 7); \
            gload_lds16(hTb + (size_t)o_ * NN + (J0) + sg_ * 8, &Hs[wv * 32 + i_ * 4][0]); } }

    // prefetch regs (named scalars -> stay in VGPRs, rule 20)
    i32x4 ca0, ca1, ca2, ca3, na0, na1, na2, na3;
    f32x4 cd0, cd1, cd2, cd3, nd0, nd1, nd2, nd3;

    // prologue: adj/dst(0) then glds(0)  -> ledger [adj x8][glds x8]
    ld4x16_i(adjrow + q * 16, ca0, ca1, ca2, ca3);
    ld4x16_f(dstb + q * 16, cd0, cd1, cd2, cd3);
    STAGE_HS(0);

    const int NT = NN / 128;   // 16
    for (int tt = 0; tt < NT; ++tt) {
        const int j0 = tt * 128;
        // 1. adj/dst(t) regs ready (8 oldest retired)
        asm volatile("s_waitcnt vmcnt(8)" ::: "memory");
        __builtin_amdgcn_sched_barrier(0);

        // 2. P-gen from registers
        {
            u16 pb[16];
            #define PGEN(AV, DV, BASE) { \
                _Pragma("unroll") for (int u_ = 0; u_ < 4; ++u_) { \
                    float e_ = src_i + (DV)[u_]; \
                    e_ = e_ > 0.f ? e_ : ALPHA * e_; \
                    float p_ = __expf(e_); \
                    p_ = ((AV)[u_] > 0) ? p_ : 0.f; \
                    const u16 pv_ = f2bf(p_); \
                    pb[(BASE) + u_] = pv_; \
                    lacc += bf2f(pv_); } }
            PGEN(ca0, cd0, 0) PGEN(ca1, cd1, 4) PGEN(ca2, cd2, 8) PGEN(ca3, cd3, 12)
            #undef PGEN
            uint4 w0, w1;
            w0.x = (uint32_t)pb[0]  | ((uint32_t)pb[1]  << 16);
            w0.y = (uint32_t)pb[2]  | ((uint32_t)pb[3]  << 16);
            w0.z = (uint32_t)pb[4]  | ((uint32_t)pb[5]  << 16);
            w0.w = (uint32_t)pb[6]  | ((uint32_t)pb[7]  << 16);
            w1.x = (uint32_t)pb[8]  | ((uint32_t)pb[9]  << 16);
            w1.y = (uint32_t)pb[10] | ((uint32_t)pb[11] << 16);
            w1.z = (uint32_t)pb[12] | ((uint32_t)pb[13] << 16);
            w1.w = (uint32_t)pb[14] | ((uint32_t)pb[15] << 16);
            *(uint4*)&Ps[il][q * 16]     = w0;
            *(uint4*)&Ps[il][q * 16 + 8] = w1;
        }

        // 3. prefetch adj/dst(t+1) — fly across both barriers
        if (tt + 1 < NT) {
            ld4x16_i(adjrow + j0 + 128 + q * 16, na0, na1, na2, na3);
            ld4x16_f(dstb + j0 + 128 + q * 16, nd0, nd1, nd2, nd3);
        }

        // 4. glds(t) landed + Ps visible; barrier
        if (tt + 1 < NT) asm volatile("s_waitcnt vmcnt(8) lgkmcnt(0)" ::: "memory");
        else             asm volatile("s_waitcnt vmcnt(0) lgkmcnt(0)" ::: "memory");
        __builtin_amdgcn_sched_barrier(0);
        __builtin_amdgcn_s_barrier();
        __builtin_amdgcn_sched_barrier(0);

        // 5. PV: wave (rowt, colt): acc += P[rowt..+16] · h[colt..+64]
        __builtin_amdgcn_s_setprio(1);
        #pragma unroll
        for (int kc = 0; kc < 4; ++kc) {
            const int ko = kc * 32 + quad * 8;
            bf16x8 a = *(const bf16x8*)&Ps[rowt + lr][ko];
            #pragma unroll
            for (int t8 = 0; t8 < 4; ++t8) {
                // row = colt + t8*16 + lr; (row & 7) == (lr & 7) == sw
                bf16x8 bb = *(const bf16x8*)&Hs[colt + t8 * 16 + lr][((kc * 4 + quad) ^ sw) * 8];
                acc[t8] = __builtin_amdgcn_mfma_f32_16x16x32_bf16(a, bb, acc[t8], 0, 0, 0);
            }
        }
        __builtin_amdgcn_s_setprio(0);

        // 6. my LDS reads done; barrier -> buffers free
        asm volatile("s_waitcnt lgkmcnt(0)" ::: "memory");
        __builtin_amdgcn_sched_barrier(0);
        __builtin_amdgcn_s_barrier();
        __builtin_amdgcn_sched_barrier(0);

        // 7. stage Hs(t+1)
        if (tt + 1 < NT) STAGE_HS(j0 + 128);

        // rotate prefetch regs (SSA rename, no movs)
        ca0 = na0; ca1 = na1; ca2 = na2; ca3 = na3;
        cd0 = nd0; cd1 = nd1; cd2 = nd2; cd3 = nd3;
    }
    #undef STAGE_HS

    lred[il][q] = lacc;
    __syncthreads();
    if (t < 32) {
        float s = 0.f;
        #pragma unroll
        for (int k = 0; k < 8; ++k) s += lred[t][k];
        lrowS[t] = s;
    }
    __syncthreads();

    // epilogue: normalize, ELU, fp32 store
    #pragma unroll
    for (int t8 = 0; t8 < 4; ++t8) {
        const int col = colt + t8 * 16 + lr;
        #pragma unroll
        for (int reg = 0; reg < 4; ++reg) {
            const int row = rowt + quad * 4 + reg;
            const float l = fmaxf(lrowS[row], 1e-30f);
            float v = acc[t8][reg] / l;
            v = v > 0.f ? v : __expf(v) - 1.f;
            out[(size_t)(b * NN + i0 + row) * FF + col] = v;
        }
    }
}

// ---------------------------------------------------------------------------
extern "C" void kernel_launch(void* const* d_in, const int* in_sizes, int n_in,
                              void* d_out, int out_size, void* d_ws, size_t ws_size,
                              hipStream_t stream) {
    const float* x = nullptr; const int* adj = nullptr; const float* w = nullptr;
    const float* as_ = nullptr; const float* ad_ = nullptr;
    for (int i = 0; i < n_in; ++i) {
        const long long s = in_sizes[i];
        if      (s == (long long)NB * NN * FF)  x   = (const float*)d_in[i];
        else if (s == (long long)NB * NN * NN)  adj = (const int*)d_in[i];
        else if (s == FF * FF)                  w   = (const float*)d_in[i];
        else if (s == FF) { if (!as_) as_ = (const float*)d_in[i]; else ad_ = (const float*)d_in[i]; }
    }
    if (!x)   x   = (const float*)d_in[0];
    if (!adj) adj = (const int*)d_in[1];
    if (!w)   w   = (const float*)d_in[2];
    if (!as_) as_ = (const float*)d_in[3];
    if (!ad_) ad_ = (const float*)d_in[4];
    float* out = (float*)d_out;

    u16*   hT   = (u16*)d_ws;                              // 4 MiB
    float* srcp = (float*)((char*)d_ws + (size_t)NB * FF * NN * sizeof(u16));
    float* dstp = srcp + NB * NN;                          // 64 KiB each

    k_prep<<<256, 256, 0, stream>>>(x, w, as_, ad_, hT, srcp, dstp);
    k_attn<<<512, 256, 0, stream>>>(adj, hT, srcp, dstp, out);
}